// Round 9
// baseline (58.494 us; speedup 1.0000x reference)
//
#include <hip/hip_runtime.h>
#include <stdint.h>

// JAX reproduction (verified bit-exact R2/R4/R5/R6/R7/R8):
//   partitionable split: subkey[j] = threefry(key,0,j); bits[i] = fold o0^o1.
// R4: disjointness merged 5 streams -> 3 threefry/element.
// R5: intra-wave compaction: streams 34/5 only for 'hit' items (P~0.09).
// R7: cndmask chain + ballot broadcast; 8 elem/thread.
// R8: helper-scatter (weights are ints 0..7; non-hit out == w verbatim).
// R9: bulk store issued BEFORE the threefry loop so the ordering
//     s_waitcnt vmcnt(0) retires ~free (store-ack hidden under ~600 cycles
//     of compute). Diagnosed from R8's VALUBusy 89->80% drop.

#define N_TOTAL 16777216
#define Y_SIZE 16384 // COUT*R*C
#define X_SIZE 1024  // CIN*KH*KW

struct U2 { uint32_t a, b; };

// ---------- constexpr threefry (compile-time key derivation) ----------
constexpr uint32_t rotl_c(uint32_t x, int r) {
  return (x << r) | (x >> (32 - r));
}

constexpr U2 threefry_c(uint32_t k0, uint32_t k1, uint32_t x0, uint32_t x1) {
  uint32_t ks2 = k0 ^ k1 ^ 0x1BD11BDAu;
  x0 += k0; x1 += k1;
  x0 += x1; x1 = rotl_c(x1, 13); x1 ^= x0;
  x0 += x1; x1 = rotl_c(x1, 15); x1 ^= x0;
  x0 += x1; x1 = rotl_c(x1, 26); x1 ^= x0;
  x0 += x1; x1 = rotl_c(x1, 6);  x1 ^= x0;
  x0 += k1; x1 += ks2 + 1u;
  x0 += x1; x1 = rotl_c(x1, 17); x1 ^= x0;
  x0 += x1; x1 = rotl_c(x1, 29); x1 ^= x0;
  x0 += x1; x1 = rotl_c(x1, 16); x1 ^= x0;
  x0 += x1; x1 = rotl_c(x1, 24); x1 ^= x0;
  x0 += ks2; x1 += k0 + 2u;
  x0 += x1; x1 = rotl_c(x1, 13); x1 ^= x0;
  x0 += x1; x1 = rotl_c(x1, 15); x1 ^= x0;
  x0 += x1; x1 = rotl_c(x1, 26); x1 ^= x0;
  x0 += x1; x1 = rotl_c(x1, 6);  x1 ^= x0;
  x0 += k0; x1 += k1 + 3u;
  x0 += x1; x1 = rotl_c(x1, 17); x1 ^= x0;
  x0 += x1; x1 = rotl_c(x1, 29); x1 ^= x0;
  x0 += x1; x1 = rotl_c(x1, 16); x1 ^= x0;
  x0 += x1; x1 = rotl_c(x1, 24); x1 ^= x0;
  x0 += k1; x1 += ks2 + 4u;
  x0 += x1; x1 = rotl_c(x1, 13); x1 ^= x0;
  x0 += x1; x1 = rotl_c(x1, 15); x1 ^= x0;
  x0 += x1; x1 = rotl_c(x1, 26); x1 ^= x0;
  x0 += x1; x1 = rotl_c(x1, 6);  x1 ^= x0;
  x0 += ks2; x1 += k0 + 5u;
  return {x0, x1};
}

constexpr U2 SK1 = threefry_c(0u, 42u, 0u, 0u); // bern_plus
constexpr U2 SK2 = threefry_c(0u, 42u, 0u, 1u); // bern_minus
constexpr U2 SK3 = threefry_c(0u, 42u, 0u, 2u); // F_minus_raw
constexpr U2 SK4 = threefry_c(0u, 42u, 0u, 3u); // F_plus_raw
constexpr U2 SK5 = threefry_c(0u, 42u, 0u, 4u); // umin

constexpr uint32_t KS2_1 = SK1.a ^ SK1.b ^ 0x1BD11BDAu;
constexpr uint32_t KS2_2 = SK2.a ^ SK2.b ^ 0x1BD11BDAu;
constexpr uint32_t KS2_3 = SK3.a ^ SK3.b ^ 0x1BD11BDAu;
constexpr uint32_t KS2_4 = SK4.a ^ SK4.b ^ 0x1BD11BDAu;
constexpr uint32_t KS2_5 = SK5.a ^ SK5.b ^ 0x1BD11BDAu;

// u < p  <=>  bits < (ceil(p*2^23) << 9)   (exact)
constexpr uint32_t bern_thr(float pf) {
  double p8 = (double)pf * 8388608.0;
  uint64_t t = (uint64_t)p8;
  if ((double)t < p8) t += 1u;
  return (uint32_t)(t << 9);
}
constexpr uint32_t T_SEARCH  = bern_thr(0.032f);
constexpr uint32_t T_CAPTURE = bern_thr(0.102f);
constexpr uint32_t T_BACKOFF = bern_thr(0.96f);
constexpr uint32_t T_MINUS   = bern_thr(0.051f);
constexpr uint32_t T_UMIN    = bern_thr(0.008f);

__device__ __forceinline__ uint32_t rotl_d(uint32_t x, int r) {
  return __builtin_amdgcn_alignbit(x, x, 32 - r);
}

// threefry fold with precomputed ks2 (keys may be VGPR or SGPR)
__device__ __forceinline__ uint32_t tf_fold_k(uint32_t k0, uint32_t k1,
                                              uint32_t ks2, uint32_t ctr) {
  uint32_t x0 = k0;        // 0 + k0
  uint32_t x1 = ctr + k1;
  x0 += x1; x1 = rotl_d(x1, 13); x1 ^= x0;
  x0 += x1; x1 = rotl_d(x1, 15); x1 ^= x0;
  x0 += x1; x1 = rotl_d(x1, 26); x1 ^= x0;
  x0 += x1; x1 = rotl_d(x1, 6);  x1 ^= x0;
  x0 += k1; x1 += ks2 + 1u;
  x0 += x1; x1 = rotl_d(x1, 17); x1 ^= x0;
  x0 += x1; x1 = rotl_d(x1, 29); x1 ^= x0;
  x0 += x1; x1 = rotl_d(x1, 16); x1 ^= x0;
  x0 += x1; x1 = rotl_d(x1, 24); x1 ^= x0;
  x0 += ks2; x1 += k0 + 2u;
  x0 += x1; x1 = rotl_d(x1, 13); x1 ^= x0;
  x0 += x1; x1 = rotl_d(x1, 15); x1 ^= x0;
  x0 += x1; x1 = rotl_d(x1, 26); x1 ^= x0;
  x0 += x1; x1 = rotl_d(x1, 6);  x1 ^= x0;
  x0 += k0; x1 += k1 + 3u;
  x0 += x1; x1 = rotl_d(x1, 17); x1 ^= x0;
  x0 += x1; x1 = rotl_d(x1, 29); x1 ^= x0;
  x0 += x1; x1 = rotl_d(x1, 16); x1 ^= x0;
  x0 += x1; x1 = rotl_d(x1, 24); x1 ^= x0;
  x0 += k1; x1 += ks2 + 4u;
  x0 += x1; x1 = rotl_d(x1, 13); x1 ^= x0;
  x0 += x1; x1 = rotl_d(x1, 15); x1 ^= x0;
  x0 += x1; x1 = rotl_d(x1, 26); x1 ^= x0;
  x0 += x1; x1 = rotl_d(x1, 6);  x1 ^= x0;
  x0 += ks2; x1 += k0 + 5u;
  return x0 ^ x1;
}

__device__ __forceinline__ float bits_to_unit_float(uint32_t bits) {
  uint32_t fb = (bits >> 9) | 0x3f800000u;
  return __uint_as_float(fb) - 1.0f;
}

__device__ __forceinline__ uint32_t mbcnt64(uint64_t m) {
  return __builtin_amdgcn_mbcnt_hi((uint32_t)(m >> 32),
         __builtin_amdgcn_mbcnt_lo((uint32_t)m, 0u));
}

// ---------- precompute x_times (1024) and y_times (16384) ----------
__global__ void precompute_times(const int* __restrict__ in_sp,
                                 const int* __restrict__ out_sp,
                                 int* __restrict__ xt, int* __restrict__ yt) {
  int tid = blockIdx.x * 256 + threadIdx.x;
  if (tid < Y_SIZE) {
    int s = 0;
#pragma unroll
    for (int t = 0; t < 7; ++t) s += out_sp[t * Y_SIZE + tid];
    yt[tid] = 7 - s;
  } else if (tid < Y_SIZE + X_SIZE) {
    int j = tid - Y_SIZE;
    int s = 0;
#pragma unroll
    for (int t = 0; t < 7; ++t) s += in_sp[t * X_SIZE + j];
    xt[j] = 7 - s;
  }
}

// ---------- main kernel: 8 elem/thread; store-early helper-scatter ----------
__global__ __launch_bounds__(256) void modstdp8e(const float* __restrict__ w,
                                                 const int* __restrict__ xt,
                                                 const int* __restrict__ yt,
                                                 float* __restrict__ out) {
  __shared__ uint32_t rec[4 * 512]; // per-wave 512 slots: ctr|w<<24|selM<<27

  uint32_t tid = threadIdx.x;
  uint32_t lane = tid & 63u;
  uint32_t ws = tid >> 6;
  uint32_t t = blockIdx.x * 256u + tid;
  uint32_t i0 = t * 8u;

  float4 wa = *reinterpret_cast<const float4*>(w + i0);
  float4 wb = *reinterpret_cast<const float4*>(w + i0 + 4u);
  int4 xa = *reinterpret_cast<const int4*>(xt + (i0 & 1023u));
  int4 xb = *reinterpret_cast<const int4*>(xt + (i0 & 1023u) + 4u);

  // bulk store NOW: non-hit outputs are exactly w (ints 0..7, clip no-op).
  // The ~600-cycle threefry phase below hides the store ack, making the
  // ordering wait before the scatter ~free.
  *reinterpret_cast<float4*>(out + i0) = wa;
  *reinterpret_cast<float4*>(out + i0 + 4u) = wb;

  float warr[8];
  *reinterpret_cast<float4*>(warr) = wa;
  *reinterpret_cast<float4*>(warr + 4) = wb;
  int barr[8];
  *reinterpret_cast<int4*>(barr) = xa;
  *reinterpret_cast<int4*>(barr + 4) = xb;

  // 8 consecutive elements share cout,r,c -> one yt lookup
  uint32_t cout = (i0 >> 10) & 63u;
  uint32_t c = (i0 >> 16) & 15u;
  uint32_t r = i0 >> 20;
  int by = yt[cout * 256u + r * 16u + c];
  bool B = (by == 7);
  // selM = !B && (bx > min(by,6)): fold !B into the gate (bx<=7 < 8)
  int gate = B ? 8 : min(by, 6);
  uint32_t tNS_A = B ? 0u : T_CAPTURE;
  uint32_t tNS_nA = B ? T_SEARCH : T_CAPTURE;

  uint32_t cnt = 0;

#pragma unroll
  for (int e = 0; e < 8; ++e) {
    uint32_t i = i0 + (uint32_t)e;
    int bx = barr[e];
    bool A = (bx == 7);
    bool selm = bx > gate;
    uint32_t tS = A ? T_BACKOFF : T_MINUS;
    uint32_t tN = A ? tNS_A : tNS_nA;
    uint32_t thr = selm ? tS : tN;
    uint32_t k0 = selm ? SK2.a : SK1.a;
    uint32_t k1 = selm ? SK2.b : SK1.b;
    uint32_t ks = selm ? KS2_2 : KS2_1;
    uint32_t bits12 = tf_fold_k(k0, k1, ks, i);
    bool h = bits12 < thr;

    uint64_t m = __ballot(h);
    if (h) {
      uint32_t rk = cnt + mbcnt64(m);
      uint32_t wi = (uint32_t)warr[e]; // weights are exact ints 0..7
      rec[ws * 512u + rk] = i | (wi << 24) | (selm ? 0x08000000u : 0u);
    }
    cnt += (uint32_t)__popcll(m);
  }

  // order bulk stores before helper scatter stores (same-wave, same address);
  // by now the stores are long acked -> this retires ~immediately.
  asm volatile("s_waitcnt vmcnt(0)" ::: "memory");

  // helpers: lanes 0..cnt-1 finish one hit item each and scatter the result
  for (uint32_t base = 0; base < cnt; base += 64u) {
    uint32_t idx = base + lane;
    if (idx < cnt) {
      uint32_t rc = rec[ws * 512u + idx];
      uint32_t ctr = rc & 0x00FFFFFFu;
      uint32_t wi = (rc >> 24) & 7u;
      bool sm = (rc & 0x08000000u) != 0u;
      float wf = (float)wi;

      const float inv7 = (float)(1.0 / 7.0);
      float ratio = __fmul_rn(wf, inv7);
      float thrF = sm
          ? __fmul_rn(__fsub_rn(1.0f, ratio), __fadd_rn(1.0f, ratio))  // pFm
          : __fmul_rn(ratio, __fsub_rn(2.0f, ratio));                  // pFp
      uint32_t k0 = sm ? SK3.a : SK4.a;
      uint32_t k1 = sm ? SK3.b : SK4.b;
      uint32_t ks = sm ? KS2_3 : KS2_4;
      uint32_t b34 = tf_fold_k(k0, k1, ks, ctr);
      uint32_t b5 = tf_fold_k(SK5.a, SK5.b, KS2_5, ctr);
      bool ok = (bits_to_unit_float(b34) < thrF) | (b5 < T_UMIN);
      if (ok) {
        int nw = sm ? (int)wi - 1 : (int)wi + 1;
        nw = max(min(nw, 7), 0);
        out[ctr] = (float)nw;
      }
    }
  }
}

extern "C" void kernel_launch(void* const* d_in, const int* in_sizes, int n_in,
                              void* d_out, int out_size, void* d_ws, size_t ws_size,
                              hipStream_t stream) {
  const float* w = (const float*)d_in[0];
  const int* isp = (const int*)d_in[1];
  const int* osp = (const int*)d_in[2];
  float* out = (float*)d_out;
  int* xt = (int*)d_ws;            // 1024 ints
  int* yt = ((int*)d_ws) + X_SIZE; // 16384 ints

  precompute_times<<<(Y_SIZE + X_SIZE + 255) / 256, 256, 0, stream>>>(isp, osp, xt, yt);
  modstdp8e<<<N_TOTAL / 8 / 256, 256, 0, stream>>>(w, xt, yt, out);
}

// Round 10
// 58.117 us; speedup vs baseline: 1.0065x; 1.0065x over previous
//
#include <hip/hip_runtime.h>
#include <stdint.h>

// JAX reproduction (verified bit-exact R2/R4-R9):
//   partitionable split: subkey[j] = threefry(key,0,j); bits[i] = fold o0^o1.
// R4: disjointness merged 5 streams -> 3 threefry/element.
// R5: intra-wave compaction: streams 34/5 only for 'hit' items (P~0.09).
// R8: helper-scatter (weights are ints 0..7; non-hit out == w verbatim).
// R10: hot loop made pure straight-line (threefry + v_lshl_or mask build,
//      no ballot/exec/LDS inside); ballots+rec writes batched after; helper
//      re-gathers w[ctr] from global (rec = ctr|selM<<31 only).
//      Diagnosis: R7-R9 static cuts gave 0.05us/instr vs 0.4 earlier and
//      VALUBusy fell 105%->82% -> issue serialization from the interleaved
//      ballot/exec/SGPR-hazard machinery, not instruction count.

#define N_TOTAL 16777216
#define Y_SIZE 16384 // COUT*R*C
#define X_SIZE 1024  // CIN*KH*KW

struct U2 { uint32_t a, b; };

// ---------- constexpr threefry (compile-time key derivation) ----------
constexpr uint32_t rotl_c(uint32_t x, int r) {
  return (x << r) | (x >> (32 - r));
}

constexpr U2 threefry_c(uint32_t k0, uint32_t k1, uint32_t x0, uint32_t x1) {
  uint32_t ks2 = k0 ^ k1 ^ 0x1BD11BDAu;
  x0 += k0; x1 += k1;
  x0 += x1; x1 = rotl_c(x1, 13); x1 ^= x0;
  x0 += x1; x1 = rotl_c(x1, 15); x1 ^= x0;
  x0 += x1; x1 = rotl_c(x1, 26); x1 ^= x0;
  x0 += x1; x1 = rotl_c(x1, 6);  x1 ^= x0;
  x0 += k1; x1 += ks2 + 1u;
  x0 += x1; x1 = rotl_c(x1, 17); x1 ^= x0;
  x0 += x1; x1 = rotl_c(x1, 29); x1 ^= x0;
  x0 += x1; x1 = rotl_c(x1, 16); x1 ^= x0;
  x0 += x1; x1 = rotl_c(x1, 24); x1 ^= x0;
  x0 += ks2; x1 += k0 + 2u;
  x0 += x1; x1 = rotl_c(x1, 13); x1 ^= x0;
  x0 += x1; x1 = rotl_c(x1, 15); x1 ^= x0;
  x0 += x1; x1 = rotl_c(x1, 26); x1 ^= x0;
  x0 += x1; x1 = rotl_c(x1, 6);  x1 ^= x0;
  x0 += k0; x1 += k1 + 3u;
  x0 += x1; x1 = rotl_c(x1, 17); x1 ^= x0;
  x0 += x1; x1 = rotl_c(x1, 29); x1 ^= x0;
  x0 += x1; x1 = rotl_c(x1, 16); x1 ^= x0;
  x0 += x1; x1 = rotl_c(x1, 24); x1 ^= x0;
  x0 += k1; x1 += ks2 + 4u;
  x0 += x1; x1 = rotl_c(x1, 13); x1 ^= x0;
  x0 += x1; x1 = rotl_c(x1, 15); x1 ^= x0;
  x0 += x1; x1 = rotl_c(x1, 26); x1 ^= x0;
  x0 += x1; x1 = rotl_c(x1, 6);  x1 ^= x0;
  x0 += ks2; x1 += k0 + 5u;
  return {x0, x1};
}

constexpr U2 SK1 = threefry_c(0u, 42u, 0u, 0u); // bern_plus
constexpr U2 SK2 = threefry_c(0u, 42u, 0u, 1u); // bern_minus
constexpr U2 SK3 = threefry_c(0u, 42u, 0u, 2u); // F_minus_raw
constexpr U2 SK4 = threefry_c(0u, 42u, 0u, 3u); // F_plus_raw
constexpr U2 SK5 = threefry_c(0u, 42u, 0u, 4u); // umin

constexpr uint32_t KS2_1 = SK1.a ^ SK1.b ^ 0x1BD11BDAu;
constexpr uint32_t KS2_2 = SK2.a ^ SK2.b ^ 0x1BD11BDAu;
constexpr uint32_t KS2_3 = SK3.a ^ SK3.b ^ 0x1BD11BDAu;
constexpr uint32_t KS2_4 = SK4.a ^ SK4.b ^ 0x1BD11BDAu;
constexpr uint32_t KS2_5 = SK5.a ^ SK5.b ^ 0x1BD11BDAu;

// u < p  <=>  bits < (ceil(p*2^23) << 9)   (exact)
constexpr uint32_t bern_thr(float pf) {
  double p8 = (double)pf * 8388608.0;
  uint64_t t = (uint64_t)p8;
  if ((double)t < p8) t += 1u;
  return (uint32_t)(t << 9);
}
constexpr uint32_t T_SEARCH  = bern_thr(0.032f);
constexpr uint32_t T_CAPTURE = bern_thr(0.102f);
constexpr uint32_t T_BACKOFF = bern_thr(0.96f);
constexpr uint32_t T_MINUS   = bern_thr(0.051f);
constexpr uint32_t T_UMIN    = bern_thr(0.008f);

__device__ __forceinline__ uint32_t rotl_d(uint32_t x, int r) {
  return __builtin_amdgcn_alignbit(x, x, 32 - r);
}

// threefry fold with precomputed ks2 (keys may be VGPR or SGPR)
__device__ __forceinline__ uint32_t tf_fold_k(uint32_t k0, uint32_t k1,
                                              uint32_t ks2, uint32_t ctr) {
  uint32_t x0 = k0;        // 0 + k0
  uint32_t x1 = ctr + k1;
  x0 += x1; x1 = rotl_d(x1, 13); x1 ^= x0;
  x0 += x1; x1 = rotl_d(x1, 15); x1 ^= x0;
  x0 += x1; x1 = rotl_d(x1, 26); x1 ^= x0;
  x0 += x1; x1 = rotl_d(x1, 6);  x1 ^= x0;
  x0 += k1; x1 += ks2 + 1u;
  x0 += x1; x1 = rotl_d(x1, 17); x1 ^= x0;
  x0 += x1; x1 = rotl_d(x1, 29); x1 ^= x0;
  x0 += x1; x1 = rotl_d(x1, 16); x1 ^= x0;
  x0 += x1; x1 = rotl_d(x1, 24); x1 ^= x0;
  x0 += ks2; x1 += k0 + 2u;
  x0 += x1; x1 = rotl_d(x1, 13); x1 ^= x0;
  x0 += x1; x1 = rotl_d(x1, 15); x1 ^= x0;
  x0 += x1; x1 = rotl_d(x1, 26); x1 ^= x0;
  x0 += x1; x1 = rotl_d(x1, 6);  x1 ^= x0;
  x0 += k0; x1 += k1 + 3u;
  x0 += x1; x1 = rotl_d(x1, 17); x1 ^= x0;
  x0 += x1; x1 = rotl_d(x1, 29); x1 ^= x0;
  x0 += x1; x1 = rotl_d(x1, 16); x1 ^= x0;
  x0 += x1; x1 = rotl_d(x1, 24); x1 ^= x0;
  x0 += k1; x1 += ks2 + 4u;
  x0 += x1; x1 = rotl_d(x1, 13); x1 ^= x0;
  x0 += x1; x1 = rotl_d(x1, 15); x1 ^= x0;
  x0 += x1; x1 = rotl_d(x1, 26); x1 ^= x0;
  x0 += x1; x1 = rotl_d(x1, 6);  x1 ^= x0;
  x0 += ks2; x1 += k0 + 5u;
  return x0 ^ x1;
}

__device__ __forceinline__ float bits_to_unit_float(uint32_t bits) {
  uint32_t fb = (bits >> 9) | 0x3f800000u;
  return __uint_as_float(fb) - 1.0f;
}

__device__ __forceinline__ uint32_t mbcnt64(uint64_t m) {
  return __builtin_amdgcn_mbcnt_hi((uint32_t)(m >> 32),
         __builtin_amdgcn_mbcnt_lo((uint32_t)m, 0u));
}

// ---------- precompute x_times (1024) and y_times (16384) ----------
__global__ void precompute_times(const int* __restrict__ in_sp,
                                 const int* __restrict__ out_sp,
                                 int* __restrict__ xt, int* __restrict__ yt) {
  int tid = blockIdx.x * 256 + threadIdx.x;
  if (tid < Y_SIZE) {
    int s = 0;
#pragma unroll
    for (int t = 0; t < 7; ++t) s += out_sp[t * Y_SIZE + tid];
    yt[tid] = 7 - s;
  } else if (tid < Y_SIZE + X_SIZE) {
    int j = tid - Y_SIZE;
    int s = 0;
#pragma unroll
    for (int t = 0; t < 7; ++t) s += in_sp[t * X_SIZE + j];
    xt[j] = 7 - s;
  }
}

// ---------- main kernel: straight-line hot loop, batched compaction ----------
__global__ __launch_bounds__(256) void modstdp10(const float* __restrict__ w,
                                                 const int* __restrict__ xt,
                                                 const int* __restrict__ yt,
                                                 float* __restrict__ out) {
  __shared__ uint32_t rec[4 * 512]; // per-wave 512 slots: ctr | selM<<31

  uint32_t tid = threadIdx.x;
  uint32_t lane = tid & 63u;
  uint32_t ws = tid >> 6;
  uint32_t t = blockIdx.x * 256u + tid;
  uint32_t i0 = t * 8u;

  float4 wa = *reinterpret_cast<const float4*>(w + i0);
  float4 wb = *reinterpret_cast<const float4*>(w + i0 + 4u);
  int4 xa = *reinterpret_cast<const int4*>(xt + (i0 & 1023u));
  int4 xb = *reinterpret_cast<const int4*>(xt + (i0 & 1023u) + 4u);
  int barr[8];
  *reinterpret_cast<int4*>(barr) = xa;
  *reinterpret_cast<int4*>(barr + 4) = xb;

  // 8 consecutive elements share cout,r,c -> one yt lookup
  uint32_t cout = (i0 >> 10) & 63u;
  uint32_t c = (i0 >> 16) & 15u;
  uint32_t r = i0 >> 20;
  int by = yt[cout * 256u + r * 16u + c];
  bool B = (by == 7);
  int gate = B ? 8 : min(by, 6); // selM = bx > gate
  uint32_t tNS_A = B ? 0u : T_CAPTURE;
  uint32_t tNS_nA = B ? T_SEARCH : T_CAPTURE;

  // ---- hot loop: pure straight-line VALU, no ballot/exec/LDS ----
  uint32_t hm = 0u;  // bit (7-e) = hit of element e
  uint32_t smm = 0u; // bit (7-e) = selM of element e
#pragma unroll
  for (int e = 0; e < 8; ++e) {
    uint32_t i = i0 + (uint32_t)e;
    int bx = barr[e];
    bool A = (bx == 7);
    bool selm = bx > gate;
    uint32_t tS = A ? T_BACKOFF : T_MINUS;
    uint32_t tN = A ? tNS_A : tNS_nA;
    uint32_t thr = selm ? tS : tN;
    uint32_t k0 = selm ? SK2.a : SK1.a;
    uint32_t k1 = selm ? SK2.b : SK1.b;
    uint32_t ks = selm ? KS2_2 : KS2_1;
    uint32_t bits12 = tf_fold_k(k0, k1, ks, i);
    hm = (hm << 1) | (bits12 < thr ? 1u : 0u);
    smm = (smm << 1) | (selm ? 1u : 0u);
  }

  // bulk store: non-hit outputs are exactly w (ints 0..7, clip is a no-op);
  // ack hides under the ballot/compact block below.
  *reinterpret_cast<float4*>(out + i0) = wa;
  *reinterpret_cast<float4*>(out + i0 + 4u) = wb;

  // ---- batched compaction: 8 ballots + rec writes ----
  uint32_t cnt = 0;
#pragma unroll
  for (int b = 0; b < 8; ++b) { // bit b corresponds to element e = 7-b
    bool hb = ((hm >> b) & 1u) != 0u;
    uint64_t m = __ballot(hb);
    if (hb) {
      uint32_t rk = cnt + mbcnt64(m);
      uint32_t sel = (smm >> b) & 1u;
      rec[ws * 512u + rk] = (i0 + (uint32_t)(7 - b)) | (sel << 31);
    }
    cnt += (uint32_t)__popcll(m);
  }

  // order bulk stores before helper scatter stores (same-wave addresses)
  asm volatile("s_waitcnt vmcnt(0)" ::: "memory");

  // ---- helpers: lanes 0..cnt-1 finish one hit item each, scatter result ----
  for (uint32_t base = 0; base < cnt; base += 64u) {
    uint32_t idx = base + lane;
    if (idx < cnt) {
      uint32_t rc = rec[ws * 512u + idx];
      uint32_t ctr = rc & 0x00FFFFFFu;
      bool sm = (rc >> 31) != 0u;
      float wf = w[ctr]; // gather; latency hidden under the threefry below

      uint32_t k0 = sm ? SK3.a : SK4.a;
      uint32_t k1 = sm ? SK3.b : SK4.b;
      uint32_t ks = sm ? KS2_3 : KS2_4;
      uint32_t b34 = tf_fold_k(k0, k1, ks, ctr);
      uint32_t b5 = tf_fold_k(SK5.a, SK5.b, KS2_5, ctr);

      const float inv7 = (float)(1.0 / 7.0);
      float ratio = __fmul_rn(wf, inv7);
      float thrF = sm
          ? __fmul_rn(__fsub_rn(1.0f, ratio), __fadd_rn(1.0f, ratio))  // pFm
          : __fmul_rn(ratio, __fsub_rn(2.0f, ratio));                  // pFp
      bool ok = (bits_to_unit_float(b34) < thrF) | (b5 < T_UMIN);
      if (ok) {
        float nw = wf + (sm ? -1.0f : 1.0f);
        out[ctr] = __builtin_amdgcn_fmed3f(nw, 0.0f, 7.0f);
      }
    }
  }
}

extern "C" void kernel_launch(void* const* d_in, const int* in_sizes, int n_in,
                              void* d_out, int out_size, void* d_ws, size_t ws_size,
                              hipStream_t stream) {
  const float* w = (const float*)d_in[0];
  const int* isp = (const int*)d_in[1];
  const int* osp = (const int*)d_in[2];
  float* out = (float*)d_out;
  int* xt = (int*)d_ws;            // 1024 ints
  int* yt = ((int*)d_ws) + X_SIZE; // 16384 ints

  precompute_times<<<(Y_SIZE + X_SIZE + 255) / 256, 256, 0, stream>>>(isp, osp, xt, yt);
  modstdp10<<<N_TOTAL / 8 / 256, 256, 0, stream>>>(w, xt, yt, out);
}